// Round 3
// baseline (216.562 us; speedup 1.0000x reference)
//
#include <hip/hip_runtime.h>

// Persistence-image kernel, MI355X — column-factorized, spill-proof (R3).
// S=128, I=32 intervals, C=32 corners, R=30 -> G=900.
// img[s,g] = sum_i w_i^2 * exp(-200 * max(min_c |g-b_ic|^2, min_c |g-d_ic|^2))
// |g-p|^2 = (r_c + qx_c*gx + qy_c*gy) + |g|^2 with qx=-2px, qy=-2py, r=|p|^2.
//
// R3: R2's tensor-product factorization (p = fma(qx,gx,r) hoisted per corner,
// rows cost fma+min each -> 2.2 ops/eval) was correct but SPILLED: VGPR=36 <
// live set, WRITE_SIZE 57.6MB of scratch, VALUBusy 12%. Root cause: 8x4x10
// nested unroll over float arrays -> unroller bailed -> runtime-indexed arrays
// -> local memory (rule #20). Fix: NAMED SCALARS (cannot spill via indexing),
// 5 rows/thread, macro-expanded bodies.
// Block = (sample, interval-pair): 192 thr = 30 cols x 6 row-groups (+12 idle).
// Both intervals accumulated in-register -> no LDS combine, no 2nd barrier,
// 16 atomics/element. Grid 2048 x 3 waves = 6 waves/SIMD: whole grid
// co-resident (launch_bounds(192,6) -> VGPR cap 85 > ~55 needed: no spill).

#define RES 30
#define GPTS 900
#define NS 128
#define NI 32
#define INV29 (1.0f / 29.0f)
#define WS_STRIDE 40  // floats per sample in ws: [0..3]=box lo/hi, [8..39]=w2[i]

__global__ __launch_bounds__(128) void prep_kernel(
    const float* __restrict__ births, const float* __restrict__ deaths,
    float* __restrict__ out, float* __restrict__ ws)
{
    const int s = blockIdx.x, tid = threadIdx.x;
    __shared__ float wc[1024];
    __shared__ float red[2][4];

    const float4* b4 = (const float4*)(births + (size_t)s * 2048);
    const float4* d4 = (const float4*)(deaths + (size_t)s * 2048);
    float mnx = 3e38f, mny = 3e38f, mxx = -3e38f, mxy = -3e38f;
    #pragma unroll
    for (int k = 0; k < 4; ++k) {
        const float4 f = b4[tid + 128 * k];
        const float4 g = d4[tid + 128 * k];
        mnx = fminf(mnx, fminf(fminf(f.x, f.z), fminf(g.x, g.z)));
        mxx = fmaxf(mxx, fmaxf(fmaxf(f.x, f.z), fmaxf(g.x, g.z)));
        mny = fminf(mny, fminf(fminf(f.y, f.w), fminf(g.y, g.w)));
        mxy = fmaxf(mxy, fmaxf(fmaxf(f.y, f.w), fmaxf(g.y, g.w)));
        const int c = 2 * (tid + 128 * k);
        wc[c]     = fmaxf(fabsf(g.x - f.x), fabsf(g.y - f.y));
        wc[c + 1] = fmaxf(fabsf(g.z - f.z), fabsf(g.w - f.w));
    }
    #pragma unroll
    for (int off = 32; off > 0; off >>= 1) {
        mnx = fminf(mnx, __shfl_down(mnx, off));
        mny = fminf(mny, __shfl_down(mny, off));
        mxx = fmaxf(mxx, __shfl_down(mxx, off));
        mxy = fmaxf(mxy, __shfl_down(mxy, off));
    }
    const int wave = tid >> 6, lane = tid & 63;
    if (lane == 0) { red[wave][0] = mnx; red[wave][1] = mny; red[wave][2] = mxx; red[wave][3] = mxy; }
    __syncthreads();

    if (tid == 0) {
        const float a = fminf(red[0][0], red[1][0]);
        const float b = fminf(red[0][1], red[1][1]);
        const float c = fmaxf(red[0][2], red[1][2]);
        const float d = fmaxf(red[0][3], red[1][3]);
        const float mgx = 0.1f * (c - a), mgy = 0.1f * (d - b);
        float* w = ws + (size_t)s * WS_STRIDE;
        w[0] = a - mgx; w[1] = b - mgy; w[2] = c + mgx; w[3] = d + mgy;
    }
    if (tid < NI) {  // deterministic serial sum of 32 per-corner weights
        float ssum = 0.f;
        #pragma unroll
        for (int k = 0; k < 32; ++k) ssum += wc[tid * 32 + k];
        const float w = ssum * (1.0f / 32.0f);
        ws[(size_t)s * WS_STRIDE + 8 + tid] = w * w;
    }
    // zero this sample's output slice (kernel-node zeroing: graph-replay-safe)
    #pragma unroll
    for (int k = 0; k < 8; ++k) {
        const int g = tid + 128 * k;
        if (g < GPTS) out[(size_t)s * GPTS + g] = 0.f;
    }
}

// 5 rows updated per corner-component; named scalars only.
#define ROW5(M, Yc, P) \
    M##0 = fminf(M##0, fmaf(Yc, gy0, P)); \
    M##1 = fminf(M##1, fmaf(Yc, gy1, P)); \
    M##2 = fminf(M##2, fmaf(Yc, gy2, P)); \
    M##3 = fminf(M##3, fmaf(Yc, gy3, P)); \
    M##4 = fminf(M##4, fmaf(Yc, gy4, P));

#define CORN4(M, Xv, Yv, Rv) \
    { const float p = fmaf(Xv.x, gx, Rv.x); ROW5(M, Yv.x, p) } \
    { const float p = fmaf(Xv.y, gx, Rv.y); ROW5(M, Yv.y, p) } \
    { const float p = fmaf(Xv.z, gx, Rv.z); ROW5(M, Yv.z, p) } \
    { const float p = fmaf(Xv.w, gx, Rv.w); ROW5(M, Yv.w, p) }

__global__ __launch_bounds__(192, 6) void pimg_kernel(
    const float* __restrict__ births, const float* __restrict__ deaths,
    float* __restrict__ out, const float* __restrict__ ws)
{
    const int bid = blockIdx.x;
    const int s   = bid >> 4;
    const int i0  = (bid & 15) * 2;
    const int tid = threadIdx.x;

    __shared__ __align__(16) float Bqx[64], Bqy[64], Br[64];
    __shared__ __align__(16) float Dqx[64], Dqy[64], Dr[64];

    // corner transform for this block's 2 intervals (threads 0..63)
    if (tid < 64) {
        const size_t base = (size_t)s * 1024 + (size_t)i0 * 32 + tid;
        const float2 pb = ((const float2*)births)[base];
        Bqx[tid] = -2.f * pb.x; Bqy[tid] = -2.f * pb.y; Br[tid] = pb.x * pb.x + pb.y * pb.y;
        const float2 pd = ((const float2*)deaths)[base];
        Dqx[tid] = -2.f * pd.x; Dqy[tid] = -2.f * pd.y; Dr[tid] = pd.x * pd.x + pd.y * pd.y;
    }

    // box + weights from ws: s is block-uniform -> scalar loads
    const float* wsp = ws + (size_t)s * WS_STRIDE;
    const float lox = wsp[0], loy = wsp[1];
    const float sx  = (wsp[2] - lox) * INV29;
    const float sy  = (wsp[3] - loy) * INV29;
    const float w2a = wsp[8 + i0];
    const float w2b = wsp[8 + i0 + 1];

    __syncthreads();

    if (tid >= 180) return;  // no barriers after this point

    // thread -> (column ix, row-group h: rows 5h..5h+4)
    const int ix = tid % 30;
    const int h  = tid / 30;

    const float gx  = fmaf((float)ix, sx, lox);
    const float gxs = gx * gx;
    const float gy0 = fmaf((float)(5 * h + 0), sy, loy);
    const float gy1 = fmaf((float)(5 * h + 1), sy, loy);
    const float gy2 = fmaf((float)(5 * h + 2), sy, loy);
    const float gy3 = fmaf((float)(5 * h + 3), sy, loy);
    const float gy4 = fmaf((float)(5 * h + 4), sy, loy);
    const float gg0 = fmaf(gy0, gy0, gxs);
    const float gg1 = fmaf(gy1, gy1, gxs);
    const float gg2 = fmaf(gy2, gy2, gxs);
    const float gg3 = fmaf(gy3, gy3, gxs);
    const float gg4 = fmaf(gy4, gy4, gxs);

    float acc0 = 0.f, acc1 = 0.f, acc2 = 0.f, acc3 = 0.f, acc4 = 0.f;

    #pragma unroll 1
    for (int il = 0; il < 2; ++il) {
        const float4* BX = (const float4*)Bqx + il * 8;
        const float4* BY = (const float4*)Bqy + il * 8;
        const float4* BR = (const float4*)Br  + il * 8;
        const float4* DX = (const float4*)Dqx + il * 8;
        const float4* DY = (const float4*)Dqy + il * 8;
        const float4* DR = (const float4*)Dr  + il * 8;

        float mb0 = 3e38f, mb1 = 3e38f, mb2 = 3e38f, mb3 = 3e38f, mb4 = 3e38f;
        float md0 = 3e38f, md1 = 3e38f, md2 = 3e38f, md3 = 3e38f, md4 = 3e38f;

        #pragma unroll
        for (int q = 0; q < 8; ++q) {
            const float4 X = BX[q], Y = BY[q], R = BR[q];
            CORN4(mb, X, Y, R)
        }
        #pragma unroll
        for (int q = 0; q < 8; ++q) {
            const float4 X = DX[q], Y = DY[q], R = DR[q];
            CORN4(md, X, Y, R)
        }

        const float w2 = il ? w2b : w2a;
        {
            const float t0 = fmaxf(mb0, md0) + gg0;
            const float t1 = fmaxf(mb1, md1) + gg1;
            const float t2 = fmaxf(mb2, md2) + gg2;
            const float t3 = fmaxf(mb3, md3) + gg3;
            const float t4 = fmaxf(mb4, md4) + gg4;
            acc0 = fmaf(w2, __expf(-200.0f * t0), acc0);
            acc1 = fmaf(w2, __expf(-200.0f * t1), acc1);
            acc2 = fmaf(w2, __expf(-200.0f * t2), acc2);
            acc3 = fmaf(w2, __expf(-200.0f * t3), acc3);
            acc4 = fmaf(w2, __expf(-200.0f * t4), acc4);
        }
    }

    float* op = out + (size_t)s * GPTS + ix * RES + 5 * h;
    atomicAdd(&op[0], acc0);
    atomicAdd(&op[1], acc1);
    atomicAdd(&op[2], acc2);
    atomicAdd(&op[3], acc3);
    atomicAdd(&op[4], acc4);
}

extern "C" void kernel_launch(void* const* d_in, const int* in_sizes, int n_in,
                              void* d_out, int out_size, void* d_ws, size_t ws_size,
                              hipStream_t stream) {
    const float* births = (const float*)d_in[0];
    const float* deaths = (const float*)d_in[1];
    float* out = (float*)d_out;
    float* ws  = (float*)d_ws;

    prep_kernel<<<NS, 128, 0, stream>>>(births, deaths, out, ws);
    pimg_kernel<<<NS * 16, 192, 0, stream>>>(births, deaths, out, ws);
}